// Round 13
// baseline (199.439 us; speedup 1.0000x reference)
//
#include <hip/hip_runtime.h>
#include <hip/hip_fp16.h>

// Problem constants (fixed shapes from setup_inputs)
#define B_ 4
#define T_ 512
#define C_ 8
#define F_ 257
#define TAPS 5
#define DELAY 3
#define N_ 40          // TAPS*C
#define NA 48          // N_ + C_ (augmented: R | P)
#define TP 505         // T - DELAY - TAPS + 1
#define T0 7           // DELAY + TAPS - 1
#define BF (B_*F_)     // 1028
#define BTCF ((size_t)B_*T_*C_*F_)
#define YSH 532        // padded LDS row stride (f16x2 dwords)
#define YPAD 8         // leading zero pad (t stored at index t+YPAD)
#define ZSD 20         // z-plane dword stride per t-row (40 f16 = 20 dwords)

typedef _Float16 half8 __attribute__((ext_vector_type(8)));
typedef float floatx4 __attribute__((ext_vector_type(4)));
typedef uint32_t uint32x4 __attribute__((ext_vector_type(4)));

__device__ inline uint32_t h2mul(uint32_t a, uint32_t b) {
    __half2 r = __hmul2(__builtin_bit_cast(__half2, a), __builtin_bit_cast(__half2, b));
    return __builtin_bit_cast(uint32_t, r);
}
__device__ inline uint32_t packf16(float2 v) {
    __half2 h = __floats2half2_rn(v.x, v.y);
    return __builtin_bit_cast(uint32_t, h);
}
__device__ inline float2 unpackf16(uint32_t u) {
    __half2 h = __builtin_bit_cast(__half2, u);
    return make_float2(__low2float(h), __high2float(h));
}
__device__ inline half8 mkfrag(uint32_t a, uint32_t b, uint32_t c, uint32_t d) {
    uint32x4 v = {a, b, c, d};
    return __builtin_bit_cast(half8, v);
}
// packed upper-triangle row start: row i holds cols i..47 (+1 pad) -> 49-i entries
__device__ inline int rowoff(int i) {
    return i * 49 - ((i * (i - 1)) >> 1);
}

struct Frag { half8 X; half8 Y; };

// Build weighted re (X) / im (Y) f16 fragments from 8 consecutive interleaved
// f16x2 dwords at p, scaled by packed f16 weight pairs sw0..3. Pure value flow.
__device__ inline Frag build2(const uint32_t* p, uint32_t sw0, uint32_t sw1,
                              uint32_t sw2, uint32_t sw3) {
    uint32_t q0 = p[0], q1 = p[1], q2 = p[2], q3 = p[3];
    uint32_t q4 = p[4], q5 = p[5], q6 = p[6], q7 = p[7];
    uint32_t x0 = __builtin_amdgcn_perm(q1, q0, 0x05040100);
    uint32_t y0 = __builtin_amdgcn_perm(q1, q0, 0x07060302);
    uint32_t x1 = __builtin_amdgcn_perm(q3, q2, 0x05040100);
    uint32_t y1 = __builtin_amdgcn_perm(q3, q2, 0x07060302);
    uint32_t x2 = __builtin_amdgcn_perm(q5, q4, 0x05040100);
    uint32_t y2 = __builtin_amdgcn_perm(q5, q4, 0x07060302);
    uint32_t x3 = __builtin_amdgcn_perm(q7, q6, 0x05040100);
    uint32_t y3 = __builtin_amdgcn_perm(q7, q6, 0x07060302);
    Frag f;
    f.X = mkfrag(h2mul(x0, sw0), h2mul(x1, sw1), h2mul(x2, sw2), h2mul(x3, sw3));
    f.Y = mkfrag(h2mul(y0, sw0), h2mul(y1, sw1), h2mul(y2, sw2), h2mul(y3, sw3));
    return f;
}
// Zs row j -> dword offset into sYh (t stored at t+YPAD):
// j<40: tap=j>>3,c=j&7 -> Y[c][k+4-tap]; j>=40: Y[j-40][k+7]
__device__ inline int zs_off(int j) {
    return (j < N_) ? (j & 7) * YSH + (YPAD + 4 - (j >> 3)) : (j - N_) * YSH + (YPAD + T0);
}

// ---------------- Fully fused single kernel. R13: instruction-count attack.
// R12 refuted the barrier-latency model (phases 117->63, wall unchanged):
// the CU is issue/dependency-saturated (VALU 46% + LDS issue + lgkm stalls).
// Gram was 3400 of ~6000 VALU inst/thread, dominated by 96 build2 calls.
// R13: ks-outer/mt-inner loop swap (B frag depends only on ks) + A==B reuse
// when mt==wv -> 48 build2 calls. Per-acc MFMA order unchanged: BIT-IDENTICAL.
__global__ __launch_bounds__(256) void k_fused(const float* __restrict__ in_re,
                                               const float* __restrict__ in_im,
                                               const int* __restrict__ ilens,
                                               float* __restrict__ out_re,
                                               float* __restrict__ out_im,
                                               float* __restrict__ pow_out) {
    __shared__ uint32_t sYh[C_ * YSH];               // 17024 B f16x2, t at t+YPAD
    __shared__ __align__(16) uint32_t pool[3256];    // 13024 B, multi-phase carve:
    // bytes 0..2560:   sPow[512] f32 (stage->weights), then sGT[320] f2 (G->A-frags)
    // bytes 2560..3584: sw_pk[256] (weights->Gram)
    // bytes 3584..13024: sAugU[1180] f2 packed upper tri (Gram->G)
    // tail: zRe = pool[0..1280), zIm = pool[1280..2560) dwords ([64][ZSD] each)
    float* sPow = (float*)pool;
    float2* sGT = (float2*)pool;
    uint32_t* sw_pk = pool + 640;
    float2* sAugU = (float2*)(pool + 896);
    int tid = threadIdx.x;

    // ---- XCD-grouped bijective block swizzle (R10-proven line sharing) ----
    int bid = blockIdx.x;
    int xcd = bid & 7, slot = bid >> 3;
    int w = (xcd < 4) ? xcd * 129 + slot : 516 + (xcd - 4) * 128 + slot;
    int b = w / F_;                 // magic-mul (constant divisor)
    int f = w - b * F_;
    int ilen = ilens[b];
    const float* pre = in_re + (size_t)b * T_ * C_ * F_ + f;
    const float* pim = in_im + (size_t)b * T_ * C_ * F_ + f;

    // ---- stage: planar scalar 4B reads, f16x2 LDS writes, fp32 power ----
    {
        int t0 = tid, t1 = tid + 256;
        float s0 = 0.f, s1 = 0.f;
#pragma unroll 4
        for (int c = 0; c < C_; ++c) {
            size_t a0 = ((size_t)t0 * C_ + c) * F_;
            size_t a1 = ((size_t)t1 * C_ + c) * F_;
            float xr0 = pre[a0], xi0 = pim[a0];
            float xr1 = pre[a1], xi1 = pim[a1];
            sYh[c * YSH + YPAD + t0] = packf16(make_float2(xr0, xi0));
            sYh[c * YSH + YPAD + t1] = packf16(make_float2(xr1, xi1));
            s0 += xr0 * xr0 + xi0 * xi0;
            s1 += xr1 * xr1 + xi1 * xi1;
        }
        if (tid < 20) {
            int z = (tid < 8) ? tid : (512 + tid);   // [0..7] and [520..531]
#pragma unroll
            for (int c = 0; c < C_; ++c) sYh[c * YSH + z] = 0;
        }
        s0 = fmaxf(s0 * (1.0f / C_), 1e-6f);
        s1 = fmaxf(s1 * (1.0f / C_), 1e-6f);
        pow_out[(size_t)w * T_ + t0] = s0;           // (B,F,T), coalesced
        pow_out[(size_t)w * T_ + t1] = s1;
        sPow[t0] = s0;
        sPow[t1] = s1;
    }
    __syncthreads();

    // ---- packed f16 sqrt(1/p[k+7]) weight pairs; zero for k >= TP ----
    {
        int k0 = 2 * tid, k1 = k0 + 1;
        float w0 = (k0 < TP) ? rsqrtf(sPow[k0 + T0]) : 0.f;   // p >= 1e-6
        float w1 = (k1 < TP) ? rsqrtf(sPow[k1 + T0]) : 0.f;
        sw_pk[tid] = packf16(make_float2(w0, w1));
    }
    __syncthreads();

    // ---- Gram via MFMA: G = Zs^H Zs (48x48, K=512), Hermitian upper only.
    //      ks OUTER, mt inner with 3 live acc pairs: B built once per ks
    //      (16 builds), A built only when mt != wv (32 builds), A==B reuse
    //      when mt==wv (offsets identical). Was 96 builds. Bit-identical. ----
    int wv = tid >> 6, ln = tid & 63;
    int kg = ln >> 4;
    if (wv < 3) {
        int r16 = ln & 15;
        int offB = zs_off(wv * 16 + r16);
        int offA0 = zs_off(r16);
        int offA1 = zs_off(16 + r16);
        int offA2 = zs_off(32 + r16);
        floatx4 aRe0 = {0.f, 0.f, 0.f, 0.f}, aIm0 = {0.f, 0.f, 0.f, 0.f};
        floatx4 aRe1 = {0.f, 0.f, 0.f, 0.f}, aIm1 = {0.f, 0.f, 0.f, 0.f};
        floatx4 aRe2 = {0.f, 0.f, 0.f, 0.f}, aIm2 = {0.f, 0.f, 0.f, 0.f};
#pragma unroll 1
        for (int ks = 0; ks < 16; ++ks) {
            int kbase = ks * 32 + kg * 8;
            uint32x4 sv = *(const uint32x4*)&sw_pk[kbase >> 1];
            Frag B = build2(&sYh[offB + kbase], sv[0], sv[1], sv[2], sv[3]);
            {   // mt = 0
                Frag A;
                if (wv == 0) A = B;
                else A = build2(&sYh[offA0 + kbase], sv[0], sv[1], sv[2], sv[3]);
                half8 nYa = -A.Y;
                aRe0 = __builtin_amdgcn_mfma_f32_16x16x32_f16(A.X, B.X, aRe0, 0, 0, 0);
                aRe0 = __builtin_amdgcn_mfma_f32_16x16x32_f16(A.Y, B.Y, aRe0, 0, 0, 0);
                aIm0 = __builtin_amdgcn_mfma_f32_16x16x32_f16(A.X, B.Y, aIm0, 0, 0, 0);
                aIm0 = __builtin_amdgcn_mfma_f32_16x16x32_f16(nYa, B.X, aIm0, 0, 0, 0);
            }
            {   // mt = 1
                Frag A;
                if (wv == 1) A = B;
                else A = build2(&sYh[offA1 + kbase], sv[0], sv[1], sv[2], sv[3]);
                half8 nYa = -A.Y;
                aRe1 = __builtin_amdgcn_mfma_f32_16x16x32_f16(A.X, B.X, aRe1, 0, 0, 0);
                aRe1 = __builtin_amdgcn_mfma_f32_16x16x32_f16(A.Y, B.Y, aRe1, 0, 0, 0);
                aIm1 = __builtin_amdgcn_mfma_f32_16x16x32_f16(A.X, B.Y, aIm1, 0, 0, 0);
                aIm1 = __builtin_amdgcn_mfma_f32_16x16x32_f16(nYa, B.X, aIm1, 0, 0, 0);
            }
            {   // mt = 2
                Frag A;
                if (wv == 2) A = B;
                else A = build2(&sYh[offA2 + kbase], sv[0], sv[1], sv[2], sv[3]);
                half8 nYa = -A.Y;
                aRe2 = __builtin_amdgcn_mfma_f32_16x16x32_f16(A.X, B.X, aRe2, 0, 0, 0);
                aRe2 = __builtin_amdgcn_mfma_f32_16x16x32_f16(A.Y, B.Y, aRe2, 0, 0, 0);
                aIm2 = __builtin_amdgcn_mfma_f32_16x16x32_f16(A.X, B.Y, aIm2, 0, 0, 0);
                aIm2 = __builtin_amdgcn_mfma_f32_16x16x32_f16(nYa, B.X, aIm2, 0, 0, 0);
            }
        }
        // C/D layout: col = lane&15, row = (lane>>4)*4 + reg  [m89-verified]
        int col = wv * 16 + r16;
#pragma unroll
        for (int r = 0; r < 4; ++r) {
            int m = kg * 4 + r;
            if (col >= m) sAugU[rowoff(m) + col - m] = make_float2(aRe0[r], aIm0[r]);
        }
#pragma unroll
        for (int r = 0; r < 4; ++r) {
            int m = 16 + kg * 4 + r;
            if (col >= m) sAugU[rowoff(m) + col - m] = make_float2(aRe1[r], aIm1[r]);
        }
#pragma unroll
        for (int r = 0; r < 4; ++r) {
            int m = 32 + kg * 4 + r;
            if (m < N_ && col >= m) sAugU[rowoff(m) + col - m] = make_float2(aRe2[r], aIm2[r]);
        }
    }
    __syncthreads();

    // ---- diag loading: wave-parallel trace reduce ----
    if (tid < 64) {
        float dv = (tid < N_) ? sAugU[rowoff(tid)].x : 0.f;
#pragma unroll
        for (int off = 32; off; off >>= 1) dv += __shfl_xor(dv, off, 64);
        if (tid < N_) sAugU[rowoff(tid)].x += 1e-10f * dv / N_;
    }
    __syncthreads();

    // ---- forward elimination, TWO pivots (p,q=p+1) per barrier interval.
    //      All reads are pre-interval values; row q's single-pivot update is
    //      recomputed on the fly by consumers and its write deferred one
    //      interval (held in dq0..dq2 by the 16 ri==0 threads). ----
    {
        int ri = tid >> 4, ci = tid & 15;
        float2 dq0, dq1, dq2;
#pragma unroll 1
        for (int p = 0; p < N_ - 2; p += 2) {
            if (p > 0 && ri == 0) {          // flush deferred row p-1
                int qm = p - 1, roqm = rowoff(qm);
                if (ci < NA - qm)      sAugU[roqm + ci] = dq0;
                if (ci + 16 < NA - qm) sAugU[roqm + ci + 16] = dq1;
                if (ci + 32 < NA - qm) sAugU[roqm + ci + 32] = dq2;
            }
            int q = p + 1;
            int rop = rowoff(p), roq = rowoff(q);
            float2 Upp = sAugU[rop];
            float2 Upq = sAugU[rop + 1];
            float2 Uqq = sAugU[roq];
            float dn0 = Upp.x * Upp.x + Upp.y * Upp.y;
            float i0x = Upp.x / dn0, i0y = -Upp.y / dn0;
            float mqx = Upq.x * i0x + Upq.y * i0y;     // m0q = conj(Upq)*inv0
            float mqy = Upq.x * i0y - Upq.y * i0x;
            float d1x = Uqq.x - (mqx * Upq.x - mqy * Upq.y);   // U1[q][q]
            float d1y = Uqq.y - (mqx * Upq.y + mqy * Upq.x);
            float dn1 = d1x * d1x + d1y * d1y;
            float i1x = d1x / dn1, i1y = -d1y / dn1;
#pragma unroll 1
            for (int i = q + ri; i < N_; i += 16) {
                if (i == q) {                 // row q -> regs (deferred write)
#pragma unroll
                    for (int s = 0; s < 3; ++s) {
                        int j = q + ci + 16 * s;
                        float2 r = make_float2(0.f, 0.f);
                        if (j < NA) {
                            float2 Upj = sAugU[rop + j - p];
                            float2 Uqj = sAugU[roq + j - q];
                            r.x = Uqj.x - (mqx * Upj.x - mqy * Upj.y);
                            r.y = Uqj.y - (mqx * Upj.y + mqy * Upj.x);
                        }
                        if (s == 0) dq0 = r; else if (s == 1) dq1 = r; else dq2 = r;
                    }
                } else {                      // rows i>=p+2: double update
                    float2 Upi = sAugU[rop + i - p];
                    float m0x = Upi.x * i0x + Upi.y * i0y;     // conj(Upi)*inv0
                    float m0y = Upi.x * i0y - Upi.y * i0x;
                    float2 Uqi = sAugU[roq + i - q];
                    float ax = Uqi.x - (m0x * Upq.x - m0y * Upq.y);   // A1[i][q]
                    float ay = -Uqi.y - (m0x * Upq.y + m0y * Upq.x);
                    float m1x = ax * i1x - ay * i1y;           // m1 = a*inv1
                    float m1y = ax * i1y + ay * i1x;
                    int roi = rowoff(i) - i;
#pragma unroll 1
                    for (int j = i + ci; j < NA; j += 16) {
                        float2 Upj = sAugU[rop + j - p];
                        float2 Uqj = sAugU[roq + j - q];
                        float u1x = Uqj.x - (mqx * Upj.x - mqy * Upj.y);
                        float u1y = Uqj.y - (mqx * Upj.y + mqy * Upj.x);
                        float2 v = sAugU[roi + j];
                        v.x -= (m0x * Upj.x - m0y * Upj.y) + (m1x * u1x - m1y * u1y);
                        v.y -= (m0x * Upj.y + m0y * Upj.x) + (m1x * u1y + m1y * u1x);
                        sAugU[roi + j] = v;
                    }
                }
            }
            __syncthreads();
        }
        // final single pivot p=38 (+ flush deferred row 37)
        {
            int p = N_ - 2;
            if (ri == 0) {
                int qm = p - 1, roqm = rowoff(qm);
                if (ci < NA - qm)      sAugU[roqm + ci] = dq0;
                if (ci + 16 < NA - qm) sAugU[roqm + ci + 16] = dq1;
                if (ci + 32 < NA - qm) sAugU[roqm + ci + 32] = dq2;
            }
            int rop = rowoff(p);
            float2 piv = sAugU[rop];
            float dn = piv.x * piv.x + piv.y * piv.y;
            float px = piv.x / dn, py = -piv.y / dn;
#pragma unroll 1
            for (int i = p + 1 + ri; i < N_; i += 16) {
                float2 api = sAugU[rop + i - p];
                float mx = api.x * px + api.y * py;
                float my = api.x * py - api.y * px;
                int roi = rowoff(i) - i;
#pragma unroll 1
                for (int j = i + ci; j < NA; j += 16) {
                    float2 apj = sAugU[rop + j - p];
                    float2 v = sAugU[roi + j];
                    v.x -= mx * apj.x - my * apj.y;
                    v.y -= mx * apj.y + my * apj.x;
                    sAugU[roi + j] = v;
                }
            }
            __syncthreads();
        }
    }
    // ---- backward elimination on RHS, TWO pivots (p,q=p-1) per interval ----
    {
        int bc = tid & 7, br = tid >> 3;
        float2 defv = make_float2(0.f, 0.f);
        int defRow = -1;
#pragma unroll 1
        for (int p = N_ - 1; p >= 3; p -= 2) {
            if (defRow >= 0 && br == (defRow & 31))
                sAugU[rowoff(defRow) + N_ + bc - defRow] = defv;
            int q = p - 1;
            int rop = rowoff(p), roq = rowoff(q);
            float2 pivP = sAugU[rop];
            float dnP = pivP.x * pivP.x + pivP.y * pivP.y;
            float pPx = pivP.x / dnP, pPy = -pivP.y / dnP;
            float2 rhsP = sAugU[rop + N_ + bc - p];
            float xPx = rhsP.x * pPx - rhsP.y * pPy;
            float xPy = rhsP.x * pPy + rhsP.y * pPx;
            float2 pivQ = sAugU[roq];
            float dnQ = pivQ.x * pivQ.x + pivQ.y * pivQ.y;
            float pQx = pivQ.x / dnQ, pQy = -pivQ.y / dnQ;
            float2 Uqp = sAugU[roq + 1];                 // U[p-1][p]
            float2 rhsQ = sAugU[roq + N_ + bc - q];
            float rqx = rhsQ.x - (Uqp.x * xPx - Uqp.y * xPy);   // rhs'[q]
            float rqy = rhsQ.y - (Uqp.x * xPy + Uqp.y * xPx);
            float xQx = rqx * pQx - rqy * pQy;
            float xQy = rqx * pQy + rqy * pQx;
#pragma unroll 1
            for (int i = br; i <= p - 2; i += 32) {
                int roi = rowoff(i) - i;
                float2 Uip = sAugU[roi + p];
                float2 Uiq = sAugU[roi + q];
                float2 v = sAugU[roi + N_ + bc];
                v.x -= (Uip.x * xPx - Uip.y * xPy) + (Uiq.x * xQx - Uiq.y * xQy);
                v.y -= (Uip.x * xPy + Uip.y * xPx) + (Uiq.x * xQy + Uiq.y * xQx);
                sAugU[roi + N_ + bc] = v;
            }
            if (br == (q & 31)) defv = make_float2(rqx, rqy);
            defRow = q;
            __syncthreads();
        }
        // single pivot p=1 (+ flush deferred rhs row 2)
        {
            if (defRow >= 0 && br == (defRow & 31))
                sAugU[rowoff(defRow) + N_ + bc - defRow] = defv;
            int rop = rowoff(1);
            float2 piv = sAugU[rop];
            float dn = piv.x * piv.x + piv.y * piv.y;
            float px = piv.x / dn, py = -piv.y / dn;
            float2 rhs = sAugU[rop + N_ + bc - 1];
            float xr = rhs.x * px - rhs.y * py;
            float xi = rhs.x * py + rhs.y * px;
            if (br == 0) {
                float2 aip = sAugU[1];                   // U[0][1] (rowoff(0)=0)
                float2 v = sAugU[N_ + bc];               // rhs[0]
                v.x -= aip.x * xr - aip.y * xi;
                v.y -= aip.x * xi + aip.y * xr;
                sAugU[N_ + bc] = v;
            }
            __syncthreads();
        }
    }
    // ---- G, transposed store: sGT[e][d][tau] = RHS[j]/diag[j] (overlays sPow) ----
    for (int idx = tid; idx < N_ * C_; idx += 256) {
        int j = idx >> 3;
        int e = idx & 7;
        int roj = rowoff(j);
        float2 piv = sAugU[roj];
        float dnm = piv.x * piv.x + piv.y * piv.y;
        float pix = piv.x / dnm, piy = -piv.y / dnm;
        float2 rhs = sAugU[roj + N_ + e - j];
        int tau = j >> 3, d = j & 7;
        sGT[(e * C_ + d) * TAPS + tau] =
            make_float2(rhs.x * pix - rhs.y * piy, rhs.x * piy + rhs.y * pix);
    }
    __syncthreads();

    // ---- A fragments from sGT (f16 cast; G ~O(1), threshold 0.134) ----
    half8 aFr[2], aFi[2];
    {
        int m = ln & 15;
#pragma unroll
        for (int ks = 0; ks < 2; ++ks) {
            half8 hr = {}, hi = {};
#pragma unroll
            for (int q = 0; q < 8; ++q) {
                int j = ks * 32 + kg * 8 + q;
                float gx = 0.f, gy = 0.f;
                if (m < 8 && j < N_) {
                    float2 g = sGT[(m * C_ + (j & 7)) * TAPS + (j >> 3)];
                    gx = g.x; gy = g.y;
                }
                hr[q] = (_Float16)gx;
                hi[q] = (_Float16)gy;
            }
            aFr[ks] = hr;
            aFi[ks] = hi;
        }
    }
    __syncthreads();   // sGT reads done -> pool becomes zRe/zIm planes

    // ================= MFMA tail, both planes resident =================
    uint32_t* zRe = pool;                    // [64][ZSD]
    uint32_t* zIm = pool + 64 * ZSD;         // [64][ZSD]
    int trow = wv * 16 + (ln & 15);
#pragma unroll 1
    for (int ch = 0; ch < 8; ++ch) {
        int c0 = ch * 64;
        for (int idx = tid; idx < 1280; idx += 256) {
            int jp = idx >> 6, tl = idx & 63;
            int j0 = 2 * jp, j1 = j0 + 1;
            int base = c0 + tl + (YPAD - 3);
            uint32_t y0 = sYh[(j0 & 7) * YSH + base - (j0 >> 3)];
            uint32_t y1 = sYh[(j1 & 7) * YSH + base - (j1 >> 3)];
            zRe[tl * ZSD + jp] = __builtin_amdgcn_perm(y1, y0, 0x05040100);
            zIm[tl * ZSD + jp] = __builtin_amdgcn_perm(y1, y0, 0x07060302);
        }
        __syncthreads();
        floatx4 accR = {0.f, 0.f, 0.f, 0.f};
        floatx4 accI = {0.f, 0.f, 0.f, 0.f};
        {
            int o0 = trow * ZSD + kg * 4;
            half8 Br0 = __builtin_bit_cast(half8, *(const uint32x4*)&zRe[o0]);
            half8 Bi0 = __builtin_bit_cast(half8, *(const uint32x4*)&zIm[o0]);
            half8 Br1 = {}, Bi1 = {};
            if (kg == 0) {
                int o1 = trow * ZSD + 16;
                Br1 = __builtin_bit_cast(half8, *(const uint32x4*)&zRe[o1]);
                Bi1 = __builtin_bit_cast(half8, *(const uint32x4*)&zIm[o1]);
            }
            half8 nFi0 = -aFi[0], nFi1 = -aFi[1];
            accR = __builtin_amdgcn_mfma_f32_16x16x32_f16(aFr[0], Br0, accR, 0, 0, 0);
            accR = __builtin_amdgcn_mfma_f32_16x16x32_f16(aFr[1], Br1, accR, 0, 0, 0);
            accI = __builtin_amdgcn_mfma_f32_16x16x32_f16(aFi[0], Br0, accI, 0, 0, 0);
            accI = __builtin_amdgcn_mfma_f32_16x16x32_f16(aFi[1], Br1, accI, 0, 0, 0);
            accR = __builtin_amdgcn_mfma_f32_16x16x32_f16(nFi0, Bi0, accR, 0, 0, 0);
            accR = __builtin_amdgcn_mfma_f32_16x16x32_f16(nFi1, Bi1, accR, 0, 0, 0);
            accI = __builtin_amdgcn_mfma_f32_16x16x32_f16(aFr[0], Bi0, accI, 0, 0, 0);
            accI = __builtin_amdgcn_mfma_f32_16x16x32_f16(aFr[1], Bi1, accI, 0, 0, 0);
        }
        if (kg < 2) {
            int tg = c0 + trow;
            bool dead = (tg >= ilen);
#pragma unroll
            for (int r = 0; r < 4; ++r) {
                int e = kg * 4 + r;
                float2 cf = unpackf16(sYh[e * YSH + YPAD + tg]);
                float ex = cf.x - accR[r];
                float ey = cf.y - accI[r];
                if (dead) { ex = 0.f; ey = 0.f; }
                size_t o = (size_t)b * T_ * C_ * F_ + ((size_t)tg * C_ + e) * F_ + f;
                out_re[o] = ex;
                out_im[o] = ey;
            }
        }
        __syncthreads();   // WAR: next chunk's build overwrites planes
    }
}

extern "C" void kernel_launch(void* const* d_in, const int* in_sizes, int n_in,
                              void* d_out, int out_size, void* d_ws, size_t ws_size,
                              hipStream_t stream) {
    const float* in_re = (const float*)d_in[0];
    const float* in_im = (const float*)d_in[1];
    const int* ilens = (const int*)d_in[2];

    float* out_re = (float*)d_out;
    float* out_im = out_re + BTCF;
    float* out_pw = out_im + BTCF;   // (B,F,T) float32

    // Single fused kernel: no transposes, no workspace.
    k_fused<<<BF, 256, 0, stream>>>(in_re, in_im, ilens, out_re, out_im, out_pw);
}

// Round 14
// 195.730 us; speedup vs baseline: 1.0189x; 1.0189x over previous
//
#include <hip/hip_runtime.h>
#include <hip/hip_fp16.h>

// Problem constants (fixed shapes from setup_inputs)
#define B_ 4
#define T_ 512
#define C_ 8
#define F_ 257
#define TAPS 5
#define DELAY 3
#define N_ 40          // TAPS*C
#define NA 48          // N_ + C_ (augmented: R | P)
#define TP 505         // T - DELAY - TAPS + 1
#define T0 7           // DELAY + TAPS - 1
#define BF (B_*F_)     // 1028
#define BTCF ((size_t)B_*T_*C_*F_)
#define YSH 528        // padded LDS row stride (f16x2 dwords); max read idx 526
#define YPAD 8         // leading zero pad (t stored at index t+YPAD)
#define ZSD 20         // z-plane dword stride per t-row (40 f16 = 20 dwords)

typedef _Float16 half8 __attribute__((ext_vector_type(8)));
typedef float floatx4 __attribute__((ext_vector_type(4)));
typedef uint32_t uint32x4 __attribute__((ext_vector_type(4)));

__device__ inline uint32_t h2mul(uint32_t a, uint32_t b) {
    __half2 r = __hmul2(__builtin_bit_cast(__half2, a), __builtin_bit_cast(__half2, b));
    return __builtin_bit_cast(uint32_t, r);
}
__device__ inline uint32_t packf16(float2 v) {
    __half2 h = __floats2half2_rn(v.x, v.y);
    return __builtin_bit_cast(uint32_t, h);
}
__device__ inline float2 unpackf16(uint32_t u) {
    __half2 h = __builtin_bit_cast(__half2, u);
    return make_float2(__low2float(h), __high2float(h));
}
__device__ inline half8 mkfrag(uint32_t a, uint32_t b, uint32_t c, uint32_t d) {
    uint32x4 v = {a, b, c, d};
    return __builtin_bit_cast(half8, v);
}
// packed upper-triangle row start, NO pad: row i holds cols i..47 -> 48-i entries
__device__ inline int rowoff(int i) {
    return i * 48 - ((i * (i - 1)) >> 1);
}

struct Frag { half8 X; half8 Y; };

// Build weighted re (X) / im (Y) f16 fragments from 8 consecutive interleaved
// f16x2 dwords at p, scaled by packed f16 weight pairs sw0..3. Pure value flow.
__device__ inline Frag build2(const uint32_t* p, uint32_t sw0, uint32_t sw1,
                              uint32_t sw2, uint32_t sw3) {
    uint32_t q0 = p[0], q1 = p[1], q2 = p[2], q3 = p[3];
    uint32_t q4 = p[4], q5 = p[5], q6 = p[6], q7 = p[7];
    uint32_t x0 = __builtin_amdgcn_perm(q1, q0, 0x05040100);
    uint32_t y0 = __builtin_amdgcn_perm(q1, q0, 0x07060302);
    uint32_t x1 = __builtin_amdgcn_perm(q3, q2, 0x05040100);
    uint32_t y1 = __builtin_amdgcn_perm(q3, q2, 0x07060302);
    uint32_t x2 = __builtin_amdgcn_perm(q5, q4, 0x05040100);
    uint32_t y2 = __builtin_amdgcn_perm(q5, q4, 0x07060302);
    uint32_t x3 = __builtin_amdgcn_perm(q7, q6, 0x05040100);
    uint32_t y3 = __builtin_amdgcn_perm(q7, q6, 0x07060302);
    Frag f;
    f.X = mkfrag(h2mul(x0, sw0), h2mul(x1, sw1), h2mul(x2, sw2), h2mul(x3, sw3));
    f.Y = mkfrag(h2mul(y0, sw0), h2mul(y1, sw1), h2mul(y2, sw2), h2mul(y3, sw3));
    return f;
}
// Zs row j -> dword offset into sYh (t stored at t+YPAD):
// j<40: tap=j>>3,c=j&7 -> Y[c][k+4-tap]; j>=40: Y[j-40][k+7]
__device__ inline int zs_off(int j) {
    return (j < N_) ? (j & 7) * YSH + (YPAD + 4 - (j >> 3)) : (j - N_) * YSH + (YPAD + T0);
}

// ---------------- Fully fused single kernel. R14: occupancy attack.
// R13 post-mortem: VALUBusy DOWN + wall UP => dependency-latency-bound at
// fixed occupancy (5 blocks/CU since R8). R14 raises residency to 6 blocks/CU
// (24 waves, +20% latency hiding) by cutting LDS 30048 -> 27136 <= 27306:
//   - sGT eliminated (G divided IN PLACE into sAugU RHS slots; A-frags read
//     sAugU directly)
//   - sAugU packed without per-row pad (48-i entries)
//   - YSH 532 -> 528
//   - pool time-carved to 10240 B (max of Gram 10144 / tail 10240 phases)
// Gram reverted to R12's proven mt-outer/ks-unroll-2 form (128 us, VGPR 44).
// GATE: LDS_Block_Size must report <= 27306 or occupancy stays 5 (flat).
__global__ __launch_bounds__(256) void k_fused(const float* __restrict__ in_re,
                                               const float* __restrict__ in_im,
                                               const int* __restrict__ ilens,
                                               float* __restrict__ out_re,
                                               float* __restrict__ out_im,
                                               float* __restrict__ pow_out) {
    __shared__ uint32_t sYh[C_ * YSH];               // 16896 B f16x2, t at t+YPAD
    __shared__ __align__(16) uint32_t pool[2560];    // 10240 B, time-carved:
    // sw_pk = pool[0..256)            (weights -> Gram)
    // sPow  = pool[256..768) f32      (stage -> weights)
    // sAugU = pool[256..2536) float2  (Gram -> A-frags; 1140 entries packed)
    // zRe   = pool[0..1280), zIm = pool[1280..2560)  (tail)
    uint32_t* sw_pk = pool;
    float* sPow = (float*)(pool + 256);
    float2* sAugU = (float2*)(pool + 256);
    int tid = threadIdx.x;

    // ---- XCD-grouped bijective block swizzle (R10-proven line sharing) ----
    int bid = blockIdx.x;
    int xcd = bid & 7, slot = bid >> 3;
    int w = (xcd < 4) ? xcd * 129 + slot : 516 + (xcd - 4) * 128 + slot;
    int b = w / F_;                 // magic-mul (constant divisor)
    int f = w - b * F_;
    int ilen = ilens[b];
    const float* pre = in_re + (size_t)b * T_ * C_ * F_ + f;
    const float* pim = in_im + (size_t)b * T_ * C_ * F_ + f;

    // ---- stage: planar scalar 4B reads, f16x2 LDS writes, fp32 power ----
    {
        int t0 = tid, t1 = tid + 256;
        float s0 = 0.f, s1 = 0.f;
#pragma unroll 4
        for (int c = 0; c < C_; ++c) {
            size_t a0 = ((size_t)t0 * C_ + c) * F_;
            size_t a1 = ((size_t)t1 * C_ + c) * F_;
            float xr0 = pre[a0], xi0 = pim[a0];
            float xr1 = pre[a1], xi1 = pim[a1];
            sYh[c * YSH + YPAD + t0] = packf16(make_float2(xr0, xi0));
            sYh[c * YSH + YPAD + t1] = packf16(make_float2(xr1, xi1));
            s0 += xr0 * xr0 + xi0 * xi0;
            s1 += xr1 * xr1 + xi1 * xi1;
        }
        if (tid < 16) {
            int z = (tid < 8) ? tid : (512 + tid);   // [0..8) and [520..528)
#pragma unroll
            for (int c = 0; c < C_; ++c) sYh[c * YSH + z] = 0;
        }
        s0 = fmaxf(s0 * (1.0f / C_), 1e-6f);
        s1 = fmaxf(s1 * (1.0f / C_), 1e-6f);
        pow_out[(size_t)w * T_ + t0] = s0;           // (B,F,T), coalesced
        pow_out[(size_t)w * T_ + t1] = s1;
        sPow[t0] = s0;
        sPow[t1] = s1;
    }
    __syncthreads();

    // ---- packed f16 sqrt(1/p[k+7]) weight pairs; zero for k >= TP ----
    {
        int k0 = 2 * tid, k1 = k0 + 1;
        float w0 = (k0 < TP) ? rsqrtf(sPow[k0 + T0]) : 0.f;   // p >= 1e-6
        float w1 = (k1 < TP) ? rsqrtf(sPow[k1 + T0]) : 0.f;
        sw_pk[tid] = packf16(make_float2(w0, w1));
    }
    __syncthreads();

    // ---- Gram via MFMA: G = Zs^H Zs (48x48, K=512), Hermitian upper only.
    //      R12 form: mt outer, ks unroll 2 (proven 128us; R13's ks-outer put
    //      build chains on the MFMA critical path and regressed). ----
    int wv = tid >> 6, ln = tid & 63;
    int kg = ln >> 4;
    if (wv < 3) {
        int r16 = ln & 15;
        int offB = zs_off(wv * 16 + r16);
#pragma unroll 1
        for (int mt = 0; mt < 3; ++mt) {
            int offA = zs_off(mt * 16 + r16);
            floatx4 aRe = {0.f, 0.f, 0.f, 0.f};
            floatx4 aIm = {0.f, 0.f, 0.f, 0.f};
#pragma unroll 2
            for (int ks = 0; ks < 16; ++ks) {
                int kbase = ks * 32 + kg * 8;
                uint32x4 sv = *(const uint32x4*)&sw_pk[kbase >> 1];
                Frag B = build2(&sYh[offB + kbase], sv[0], sv[1], sv[2], sv[3]);
                Frag A = build2(&sYh[offA + kbase], sv[0], sv[1], sv[2], sv[3]);
                half8 nYa = -A.Y;
                aRe = __builtin_amdgcn_mfma_f32_16x16x32_f16(A.X, B.X, aRe, 0, 0, 0);
                aRe = __builtin_amdgcn_mfma_f32_16x16x32_f16(A.Y, B.Y, aRe, 0, 0, 0);
                aIm = __builtin_amdgcn_mfma_f32_16x16x32_f16(A.X, B.Y, aIm, 0, 0, 0);
                aIm = __builtin_amdgcn_mfma_f32_16x16x32_f16(nYa, B.X, aIm, 0, 0, 0);
            }
            // C/D layout: col = lane&15, row = (lane>>4)*4 + reg  [m89-verified]
#pragma unroll
            for (int r = 0; r < 4; ++r) {
                int m = mt * 16 + kg * 4 + r;
                int col = wv * 16 + r16;
                if (m < N_ && col >= m)
                    sAugU[rowoff(m) + col - m] = make_float2(aRe[r], aIm[r]);
            }
        }
    }
    __syncthreads();

    // ---- diag loading: wave-parallel trace reduce ----
    if (tid < 64) {
        float dv = (tid < N_) ? sAugU[rowoff(tid)].x : 0.f;
#pragma unroll
        for (int off = 32; off; off >>= 1) dv += __shfl_xor(dv, off, 64);
        if (tid < N_) sAugU[rowoff(tid)].x += 1e-10f * dv / N_;
    }
    __syncthreads();

    // ---- forward elimination, TWO pivots (p,q=p+1) per barrier interval.
    //      All reads are pre-interval values; row q's single-pivot update is
    //      recomputed on the fly by consumers and its write deferred one
    //      interval (held in dq0..dq2 by the 16 ri==0 threads). ----
    {
        int ri = tid >> 4, ci = tid & 15;
        float2 dq0, dq1, dq2;
#pragma unroll 1
        for (int p = 0; p < N_ - 2; p += 2) {
            if (p > 0 && ri == 0) {          // flush deferred row p-1
                int qm = p - 1, roqm = rowoff(qm);
                if (ci < NA - qm)      sAugU[roqm + ci] = dq0;
                if (ci + 16 < NA - qm) sAugU[roqm + ci + 16] = dq1;
                if (ci + 32 < NA - qm) sAugU[roqm + ci + 32] = dq2;
            }
            int q = p + 1;
            int rop = rowoff(p), roq = rowoff(q);
            float2 Upp = sAugU[rop];
            float2 Upq = sAugU[rop + 1];
            float2 Uqq = sAugU[roq];
            float dn0 = Upp.x * Upp.x + Upp.y * Upp.y;
            float i0x = Upp.x / dn0, i0y = -Upp.y / dn0;
            float mqx = Upq.x * i0x + Upq.y * i0y;     // m0q = conj(Upq)*inv0
            float mqy = Upq.x * i0y - Upq.y * i0x;
            float d1x = Uqq.x - (mqx * Upq.x - mqy * Upq.y);   // U1[q][q]
            float d1y = Uqq.y - (mqx * Upq.y + mqy * Upq.x);
            float dn1 = d1x * d1x + d1y * d1y;
            float i1x = d1x / dn1, i1y = -d1y / dn1;
#pragma unroll 1
            for (int i = q + ri; i < N_; i += 16) {
                if (i == q) {                 // row q -> regs (deferred write)
#pragma unroll
                    for (int s = 0; s < 3; ++s) {
                        int j = q + ci + 16 * s;
                        float2 r = make_float2(0.f, 0.f);
                        if (j < NA) {
                            float2 Upj = sAugU[rop + j - p];
                            float2 Uqj = sAugU[roq + j - q];
                            r.x = Uqj.x - (mqx * Upj.x - mqy * Upj.y);
                            r.y = Uqj.y - (mqx * Upj.y + mqy * Upj.x);
                        }
                        if (s == 0) dq0 = r; else if (s == 1) dq1 = r; else dq2 = r;
                    }
                } else {                      // rows i>=p+2: double update
                    float2 Upi = sAugU[rop + i - p];
                    float m0x = Upi.x * i0x + Upi.y * i0y;     // conj(Upi)*inv0
                    float m0y = Upi.x * i0y - Upi.y * i0x;
                    float2 Uqi = sAugU[roq + i - q];
                    float ax = Uqi.x - (m0x * Upq.x - m0y * Upq.y);   // A1[i][q]
                    float ay = -Uqi.y - (m0x * Upq.y + m0y * Upq.x);
                    float m1x = ax * i1x - ay * i1y;           // m1 = a*inv1
                    float m1y = ax * i1y + ay * i1x;
                    int roi = rowoff(i) - i;
#pragma unroll 1
                    for (int j = i + ci; j < NA; j += 16) {
                        float2 Upj = sAugU[rop + j - p];
                        float2 Uqj = sAugU[roq + j - q];
                        float u1x = Uqj.x - (mqx * Upj.x - mqy * Upj.y);
                        float u1y = Uqj.y - (mqx * Upj.y + mqy * Upj.x);
                        float2 v = sAugU[roi + j];
                        v.x -= (m0x * Upj.x - m0y * Upj.y) + (m1x * u1x - m1y * u1y);
                        v.y -= (m0x * Upj.y + m0y * Upj.x) + (m1x * u1y + m1y * u1x);
                        sAugU[roi + j] = v;
                    }
                }
            }
            __syncthreads();
        }
        // final single pivot p=38 (+ flush deferred row 37)
        {
            int p = N_ - 2;
            if (ri == 0) {
                int qm = p - 1, roqm = rowoff(qm);
                if (ci < NA - qm)      sAugU[roqm + ci] = dq0;
                if (ci + 16 < NA - qm) sAugU[roqm + ci + 16] = dq1;
                if (ci + 32 < NA - qm) sAugU[roqm + ci + 32] = dq2;
            }
            int rop = rowoff(p);
            float2 piv = sAugU[rop];
            float dn = piv.x * piv.x + piv.y * piv.y;
            float px = piv.x / dn, py = -piv.y / dn;
#pragma unroll 1
            for (int i = p + 1 + ri; i < N_; i += 16) {
                float2 api = sAugU[rop + i - p];
                float mx = api.x * px + api.y * py;
                float my = api.x * py - api.y * px;
                int roi = rowoff(i) - i;
#pragma unroll 1
                for (int j = i + ci; j < NA; j += 16) {
                    float2 apj = sAugU[rop + j - p];
                    float2 v = sAugU[roi + j];
                    v.x -= mx * apj.x - my * apj.y;
                    v.y -= mx * apj.y + my * apj.x;
                    sAugU[roi + j] = v;
                }
            }
            __syncthreads();
        }
    }
    // ---- backward elimination on RHS, TWO pivots (p,q=p-1) per interval ----
    {
        int bc = tid & 7, br = tid >> 3;
        float2 defv = make_float2(0.f, 0.f);
        int defRow = -1;
#pragma unroll 1
        for (int p = N_ - 1; p >= 3; p -= 2) {
            if (defRow >= 0 && br == (defRow & 31))
                sAugU[rowoff(defRow) + N_ + bc - defRow] = defv;
            int q = p - 1;
            int rop = rowoff(p), roq = rowoff(q);
            float2 pivP = sAugU[rop];
            float dnP = pivP.x * pivP.x + pivP.y * pivP.y;
            float pPx = pivP.x / dnP, pPy = -pivP.y / dnP;
            float2 rhsP = sAugU[rop + N_ + bc - p];
            float xPx = rhsP.x * pPx - rhsP.y * pPy;
            float xPy = rhsP.x * pPy + rhsP.y * pPx;
            float2 pivQ = sAugU[roq];
            float dnQ = pivQ.x * pivQ.x + pivQ.y * pivQ.y;
            float pQx = pivQ.x / dnQ, pQy = -pivQ.y / dnQ;
            float2 Uqp = sAugU[roq + 1];                 // U[p-1][p]
            float2 rhsQ = sAugU[roq + N_ + bc - q];
            float rqx = rhsQ.x - (Uqp.x * xPx - Uqp.y * xPy);   // rhs'[q]
            float rqy = rhsQ.y - (Uqp.x * xPy + Uqp.y * xPx);
            float xQx = rqx * pQx - rqy * pQy;
            float xQy = rqx * pQy + rqy * pQx;
#pragma unroll 1
            for (int i = br; i <= p - 2; i += 32) {
                int roi = rowoff(i) - i;
                float2 Uip = sAugU[roi + p];
                float2 Uiq = sAugU[roi + q];
                float2 v = sAugU[roi + N_ + bc];
                v.x -= (Uip.x * xPx - Uip.y * xPy) + (Uiq.x * xQx - Uiq.y * xQy);
                v.y -= (Uip.x * xPy + Uip.y * xPx) + (Uiq.x * xQy + Uiq.y * xQx);
                sAugU[roi + N_ + bc] = v;
            }
            if (br == (q & 31)) defv = make_float2(rqx, rqy);
            defRow = q;
            __syncthreads();
        }
        // single pivot p=1 (+ flush deferred rhs row 2)
        {
            if (defRow >= 0 && br == (defRow & 31))
                sAugU[rowoff(defRow) + N_ + bc - defRow] = defv;
            int rop = rowoff(1);
            float2 piv = sAugU[rop];
            float dn = piv.x * piv.x + piv.y * piv.y;
            float px = piv.x / dn, py = -piv.y / dn;
            float2 rhs = sAugU[rop + N_ + bc - 1];
            float xr = rhs.x * px - rhs.y * py;
            float xi = rhs.x * py + rhs.y * px;
            if (br == 0) {
                float2 aip = sAugU[1];                   // U[0][1] (rowoff(0)=0)
                float2 v = sAugU[N_ + bc];               // rhs[0]
                v.x -= aip.x * xr - aip.y * xi;
                v.y -= aip.x * xi + aip.y * xr;
                sAugU[N_ + bc] = v;
            }
            __syncthreads();
        }
    }
    // ---- G divide IN PLACE: rhs[j][e] /= diag[j] (same slots; diag col j and
    //      rhs cols 40+e are disjoint -> race-free). Replaces sGT (-2560 B). ----
    for (int idx = tid; idx < N_ * C_; idx += 256) {
        int j = idx >> 3;
        int e = idx & 7;
        int roj = rowoff(j);
        float2 piv = sAugU[roj];
        float dnm = piv.x * piv.x + piv.y * piv.y;
        float pix = piv.x / dnm, piy = -piv.y / dnm;
        float2 rhs = sAugU[roj + N_ + e - j];
        sAugU[roj + N_ + e - j] =
            make_float2(rhs.x * pix - rhs.y * piy, rhs.x * piy + rhs.y * pix);
    }
    __syncthreads();

    // ---- A fragments read directly from in-place G (f16 cast; threshold 0.134) ----
    half8 aFr[2], aFi[2];
    {
        int m = ln & 15;
#pragma unroll
        for (int ks = 0; ks < 2; ++ks) {
            half8 hr = {}, hi = {};
#pragma unroll
            for (int q = 0; q < 8; ++q) {
                int j = ks * 32 + kg * 8 + q;
                float gx = 0.f, gy = 0.f;
                if (m < 8 && j < N_) {
                    float2 g = sAugU[rowoff(j) + N_ + m - j];
                    gx = g.x; gy = g.y;
                }
                hr[q] = (_Float16)gx;
                hi[q] = (_Float16)gy;
            }
            aFr[ks] = hr;
            aFi[ks] = hi;
        }
    }
    __syncthreads();   // sAugU reads done -> pool becomes zRe/zIm planes

    // ================= MFMA tail, both planes resident =================
    uint32_t* zRe = pool;                    // [64][ZSD]
    uint32_t* zIm = pool + 64 * ZSD;         // [64][ZSD]
    int trow = wv * 16 + (ln & 15);
#pragma unroll 1
    for (int ch = 0; ch < 8; ++ch) {
        int c0 = ch * 64;
        for (int idx = tid; idx < 1280; idx += 256) {
            int jp = idx >> 6, tl = idx & 63;
            int j0 = 2 * jp, j1 = j0 + 1;
            int base = c0 + tl + (YPAD - 3);
            uint32_t y0 = sYh[(j0 & 7) * YSH + base - (j0 >> 3)];
            uint32_t y1 = sYh[(j1 & 7) * YSH + base - (j1 >> 3)];
            zRe[tl * ZSD + jp] = __builtin_amdgcn_perm(y1, y0, 0x05040100);
            zIm[tl * ZSD + jp] = __builtin_amdgcn_perm(y1, y0, 0x07060302);
        }
        __syncthreads();
        floatx4 accR = {0.f, 0.f, 0.f, 0.f};
        floatx4 accI = {0.f, 0.f, 0.f, 0.f};
        {
            int o0 = trow * ZSD + kg * 4;
            half8 Br0 = __builtin_bit_cast(half8, *(const uint32x4*)&zRe[o0]);
            half8 Bi0 = __builtin_bit_cast(half8, *(const uint32x4*)&zIm[o0]);
            half8 Br1 = {}, Bi1 = {};
            if (kg == 0) {
                int o1 = trow * ZSD + 16;
                Br1 = __builtin_bit_cast(half8, *(const uint32x4*)&zRe[o1]);
                Bi1 = __builtin_bit_cast(half8, *(const uint32x4*)&zIm[o1]);
            }
            half8 nFi0 = -aFi[0], nFi1 = -aFi[1];
            accR = __builtin_amdgcn_mfma_f32_16x16x32_f16(aFr[0], Br0, accR, 0, 0, 0);
            accR = __builtin_amdgcn_mfma_f32_16x16x32_f16(aFr[1], Br1, accR, 0, 0, 0);
            accI = __builtin_amdgcn_mfma_f32_16x16x32_f16(aFi[0], Br0, accI, 0, 0, 0);
            accI = __builtin_amdgcn_mfma_f32_16x16x32_f16(aFi[1], Br1, accI, 0, 0, 0);
            accR = __builtin_amdgcn_mfma_f32_16x16x32_f16(nFi0, Bi0, accR, 0, 0, 0);
            accR = __builtin_amdgcn_mfma_f32_16x16x32_f16(nFi1, Bi1, accR, 0, 0, 0);
            accI = __builtin_amdgcn_mfma_f32_16x16x32_f16(aFr[0], Bi0, accI, 0, 0, 0);
            accI = __builtin_amdgcn_mfma_f32_16x16x32_f16(aFr[1], Bi1, accI, 0, 0, 0);
        }
        if (kg < 2) {
            int tg = c0 + trow;
            bool dead = (tg >= ilen);
#pragma unroll
            for (int r = 0; r < 4; ++r) {
                int e = kg * 4 + r;
                float2 cf = unpackf16(sYh[e * YSH + YPAD + tg]);
                float ex = cf.x - accR[r];
                float ey = cf.y - accI[r];
                if (dead) { ex = 0.f; ey = 0.f; }
                size_t o = (size_t)b * T_ * C_ * F_ + ((size_t)tg * C_ + e) * F_ + f;
                out_re[o] = ex;
                out_im[o] = ey;
            }
        }
        __syncthreads();   // WAR: next chunk's build overwrites planes
    }
}

extern "C" void kernel_launch(void* const* d_in, const int* in_sizes, int n_in,
                              void* d_out, int out_size, void* d_ws, size_t ws_size,
                              hipStream_t stream) {
    const float* in_re = (const float*)d_in[0];
    const float* in_im = (const float*)d_in[1];
    const int* ilens = (const int*)d_in[2];

    float* out_re = (float*)d_out;
    float* out_im = out_re + BTCF;
    float* out_pw = out_im + BTCF;   // (B,F,T) float32

    // Single fused kernel: no transposes, no workspace.
    k_fused<<<BF, 256, 0, stream>>>(in_re, in_im, ilens, out_re, out_im, out_pw);
}

// Round 15
// 193.881 us; speedup vs baseline: 1.0287x; 1.0095x over previous
//
#include <hip/hip_runtime.h>
#include <hip/hip_fp16.h>

// Problem constants (fixed shapes from setup_inputs)
#define B_ 4
#define T_ 512
#define C_ 8
#define F_ 257
#define TAPS 5
#define DELAY 3
#define N_ 40          // TAPS*C
#define NA 48          // N_ + C_ (augmented: R | P)
#define TP 505         // T - DELAY - TAPS + 1
#define T0 7           // DELAY + TAPS - 1
#define BF (B_*F_)     // 1028
#define BTCF ((size_t)B_*T_*C_*F_)
#define YSH 532        // padded LDS row stride (f16x2 dwords); 532%32=20 spreads banks (R14: 528 tripled conflicts)
#define YPAD 8         // leading zero pad (t stored at index t+YPAD)
#define ZSD 20         // z-plane dword stride per t-row (40 f16 = 20 dwords)
#define NTHR 384       // 6 waves: Gram = 6 upper-tri tiles, 24 waves/CU at 4 blocks/CU

typedef _Float16 half8 __attribute__((ext_vector_type(8)));
typedef float floatx4 __attribute__((ext_vector_type(4)));
typedef uint32_t uint32x4 __attribute__((ext_vector_type(4)));

__device__ inline uint32_t h2mul(uint32_t a, uint32_t b) {
    __half2 r = __hmul2(__builtin_bit_cast(__half2, a), __builtin_bit_cast(__half2, b));
    return __builtin_bit_cast(uint32_t, r);
}
__device__ inline uint32_t packf16(float2 v) {
    __half2 h = __floats2half2_rn(v.x, v.y);
    return __builtin_bit_cast(uint32_t, h);
}
__device__ inline float2 unpackf16(uint32_t u) {
    __half2 h = __builtin_bit_cast(__half2, u);
    return make_float2(__low2float(h), __high2float(h));
}
__device__ inline half8 mkfrag(uint32_t a, uint32_t b, uint32_t c, uint32_t d) {
    uint32x4 v = {a, b, c, d};
    return __builtin_bit_cast(half8, v);
}
// packed upper-triangle row start (+1 pad per row): row i holds cols i..47 -> 49-i entries
__device__ inline int rowoff(int i) {
    return i * 49 - ((i * (i - 1)) >> 1);
}

struct Frag { half8 X; half8 Y; };

// Build weighted re (X) / im (Y) f16 fragments from 8 consecutive interleaved
// f16x2 dwords at p, scaled by packed f16 weight pairs sw0..3. Pure value flow.
__device__ inline Frag build2(const uint32_t* p, uint32_t sw0, uint32_t sw1,
                              uint32_t sw2, uint32_t sw3) {
    uint32_t q0 = p[0], q1 = p[1], q2 = p[2], q3 = p[3];
    uint32_t q4 = p[4], q5 = p[5], q6 = p[6], q7 = p[7];
    uint32_t x0 = __builtin_amdgcn_perm(q1, q0, 0x05040100);
    uint32_t y0 = __builtin_amdgcn_perm(q1, q0, 0x07060302);
    uint32_t x1 = __builtin_amdgcn_perm(q3, q2, 0x05040100);
    uint32_t y1 = __builtin_amdgcn_perm(q3, q2, 0x07060302);
    uint32_t x2 = __builtin_amdgcn_perm(q5, q4, 0x05040100);
    uint32_t y2 = __builtin_amdgcn_perm(q5, q4, 0x07060302);
    uint32_t x3 = __builtin_amdgcn_perm(q7, q6, 0x05040100);
    uint32_t y3 = __builtin_amdgcn_perm(q7, q6, 0x07060302);
    Frag f;
    f.X = mkfrag(h2mul(x0, sw0), h2mul(x1, sw1), h2mul(x2, sw2), h2mul(x3, sw3));
    f.Y = mkfrag(h2mul(y0, sw0), h2mul(y1, sw1), h2mul(y2, sw2), h2mul(y3, sw3));
    return f;
}
// Zs row j -> dword offset into sYh (t stored at t+YPAD):
// j<40: tap=j>>3,c=j&7 -> Y[c][k+4-tap]; j>=40: Y[j-40][k+7]
__device__ inline int zs_off(int j) {
    return (j < N_) ? (j & 7) * YSH + (YPAD + 4 - (j >> 3)) : (j - N_) * YSH + (YPAD + T0);
}

// ---------------- Fully fused single kernel. R15: waves-per-problem attack.
// R14 post-mortem: grid = 1028 blocks / 256 CUs = 4 blocks/CU -> LDS capacity
// 5 vs 6 is irrelevant; waves/CU stuck at 16 since R8. Also YSH 528 tripled
// bank conflicts (528%32=16; revert to 532). R15: 384-thread blocks (6 waves)
// -> 24 waves/CU, AND the Gram's 6 upper-tri wave-tiles map 1:1 onto 6 waves
// (16 ks-iters per wave instead of 48; diag tiles A==B single-build). Layout
// reverted to R12-proven (YSH 532, AS 49 pool 13024B) + R14's in-place G.
__global__ __launch_bounds__(NTHR) void k_fused(const float* __restrict__ in_re,
                                                const float* __restrict__ in_im,
                                                const int* __restrict__ ilens,
                                                float* __restrict__ out_re,
                                                float* __restrict__ out_im,
                                                float* __restrict__ pow_out) {
    __shared__ uint32_t sYh[C_ * YSH];               // 17024 B f16x2, t at t+YPAD
    __shared__ __align__(16) uint32_t pool[3256];    // 13024 B, time-carved:
    // sPow  = pool[0..512) f32        (stage -> weights)
    // sw_pk = pool[640..896)          (weights -> Gram)
    // sAugU = (float2*)(pool+896), 1180 entries (Gram -> A-frags; G in place)
    // zRe   = pool[0..1280), zIm = pool[1280..2560)  (tail)
    float* sPow = (float*)pool;
    uint32_t* sw_pk = pool + 640;
    float2* sAugU = (float2*)(pool + 896);
    int tid = threadIdx.x;

    // ---- XCD-grouped bijective block swizzle (R10-proven line sharing) ----
    int bid = blockIdx.x;
    int xcd = bid & 7, slot = bid >> 3;
    int w = (xcd < 4) ? xcd * 129 + slot : 516 + (xcd - 4) * 128 + slot;
    int b = w / F_;                 // magic-mul (constant divisor)
    int f = w - b * F_;
    int ilen = ilens[b];
    const float* pre = in_re + (size_t)b * T_ * C_ * F_ + f;
    const float* pim = in_im + (size_t)b * T_ * C_ * F_ + f;

    // ---- stage: planar scalar 4B reads, f16x2 LDS writes, fp32 power ----
    {
#pragma unroll 1
        for (int t = tid; t < T_; t += NTHR) {
            float sacc = 0.f;
#pragma unroll 4
            for (int c = 0; c < C_; ++c) {
                size_t a = ((size_t)t * C_ + c) * F_;
                float xr = pre[a], xi = pim[a];
                sYh[c * YSH + YPAD + t] = packf16(make_float2(xr, xi));
                sacc += xr * xr + xi * xi;
            }
            sacc = fmaxf(sacc * (1.0f / C_), 1e-6f);
            pow_out[(size_t)w * T_ + t] = sacc;      // (B,F,T), coalesced
            sPow[t] = sacc;
        }
        if (tid < 20) {
            int z = (tid < 8) ? tid : (512 + tid);   // [0..8) and [520..532)
#pragma unroll
            for (int c = 0; c < C_; ++c) sYh[c * YSH + z] = 0;
        }
    }
    __syncthreads();

    // ---- packed f16 sqrt(1/p[k+7]) weight pairs; zero for k >= TP ----
    if (tid < 256) {
        int k0 = 2 * tid, k1 = k0 + 1;
        float w0 = (k0 < TP) ? rsqrtf(sPow[k0 + T0]) : 0.f;   // p >= 1e-6
        float w1 = (k1 < TP) ? rsqrtf(sPow[k1 + T0]) : 0.f;
        sw_pk[tid] = packf16(make_float2(w0, w1));
    }
    __syncthreads();

    // ---- Gram via MFMA: G = Zs^H Zs (48x48, K=512), Hermitian upper only.
    //      6 waves <-> 6 upper-tri 16x16 tiles; each wave 16 ks-iterations
    //      (was 48). Diagonal tiles: A == B (offsets identical), one build. ----
    int wv = tid / 64, ln = tid & 63;
    int kg = ln >> 4;
    {
        int r16 = ln & 15;
        // tile map: 0:(0,0) 1:(0,1) 2:(0,2) 3:(1,1) 4:(1,2) 5:(2,2)
        int mt = (wv < 3) ? 0 : ((wv < 5) ? 1 : 2);
        int nt = (wv < 3) ? wv : ((wv < 5) ? wv - 2 : 2);
        bool diag = (mt == nt);
        int offB = zs_off(nt * 16 + r16);
        int offA = zs_off(mt * 16 + r16);
        floatx4 aRe = {0.f, 0.f, 0.f, 0.f};
        floatx4 aIm = {0.f, 0.f, 0.f, 0.f};
#pragma unroll 2
        for (int ks = 0; ks < 16; ++ks) {
            int kbase = ks * 32 + kg * 8;
            uint32x4 sv = *(const uint32x4*)&sw_pk[kbase >> 1];
            Frag B = build2(&sYh[offB + kbase], sv[0], sv[1], sv[2], sv[3]);
            Frag A;
            if (diag) A = B;    // wave-uniform branch
            else A = build2(&sYh[offA + kbase], sv[0], sv[1], sv[2], sv[3]);
            half8 nYa = -A.Y;
            aRe = __builtin_amdgcn_mfma_f32_16x16x32_f16(A.X, B.X, aRe, 0, 0, 0);
            aRe = __builtin_amdgcn_mfma_f32_16x16x32_f16(A.Y, B.Y, aRe, 0, 0, 0);
            aIm = __builtin_amdgcn_mfma_f32_16x16x32_f16(A.X, B.Y, aIm, 0, 0, 0);
            aIm = __builtin_amdgcn_mfma_f32_16x16x32_f16(nYa, B.X, aIm, 0, 0, 0);
        }
        // C/D layout: col = lane&15, row = (lane>>4)*4 + reg  [m89-verified]
        int col = nt * 16 + r16;
#pragma unroll
        for (int r = 0; r < 4; ++r) {
            int m = mt * 16 + kg * 4 + r;
            if (m < N_ && col >= m)
                sAugU[rowoff(m) + col - m] = make_float2(aRe[r], aIm[r]);
        }
    }
    __syncthreads();

    // ---- diag loading: wave-parallel trace reduce ----
    if (tid < 64) {
        float dv = (tid < N_) ? sAugU[rowoff(tid)].x : 0.f;
#pragma unroll
        for (int off = 32; off; off >>= 1) dv += __shfl_xor(dv, off, 64);
        if (tid < N_) sAugU[rowoff(tid)].x += 1e-10f * dv / N_;
    }
    __syncthreads();

    // ---- forward elimination, TWO pivots (p,q=p+1) per barrier interval.
    //      24 row-groups x 16 col-groups (384 threads). Row q's single-pivot
    //      update recomputed on the fly; write deferred one interval (dq regs
    //      in the 16 ri==0 threads). ----
    {
        int ri = tid >> 4, ci = tid & 15;    // ri 0..23
        float2 dq0, dq1, dq2;
#pragma unroll 1
        for (int p = 0; p < N_ - 2; p += 2) {
            if (p > 0 && ri == 0) {          // flush deferred row p-1
                int qm = p - 1, roqm = rowoff(qm);
                if (ci < NA - qm)      sAugU[roqm + ci] = dq0;
                if (ci + 16 < NA - qm) sAugU[roqm + ci + 16] = dq1;
                if (ci + 32 < NA - qm) sAugU[roqm + ci + 32] = dq2;
            }
            int q = p + 1;
            int rop = rowoff(p), roq = rowoff(q);
            float2 Upp = sAugU[rop];
            float2 Upq = sAugU[rop + 1];
            float2 Uqq = sAugU[roq];
            float dn0 = Upp.x * Upp.x + Upp.y * Upp.y;
            float i0x = Upp.x / dn0, i0y = -Upp.y / dn0;
            float mqx = Upq.x * i0x + Upq.y * i0y;     // m0q = conj(Upq)*inv0
            float mqy = Upq.x * i0y - Upq.y * i0x;
            float d1x = Uqq.x - (mqx * Upq.x - mqy * Upq.y);   // U1[q][q]
            float d1y = Uqq.y - (mqx * Upq.y + mqy * Upq.x);
            float dn1 = d1x * d1x + d1y * d1y;
            float i1x = d1x / dn1, i1y = -d1y / dn1;
#pragma unroll 1
            for (int i = q + ri; i < N_; i += 24) {
                if (i == q) {                 // row q -> regs (deferred write)
#pragma unroll
                    for (int s = 0; s < 3; ++s) {
                        int j = q + ci + 16 * s;
                        float2 r = make_float2(0.f, 0.f);
                        if (j < NA) {
                            float2 Upj = sAugU[rop + j - p];
                            float2 Uqj = sAugU[roq + j - q];
                            r.x = Uqj.x - (mqx * Upj.x - mqy * Upj.y);
                            r.y = Uqj.y - (mqx * Upj.y + mqy * Upj.x);
                        }
                        if (s == 0) dq0 = r; else if (s == 1) dq1 = r; else dq2 = r;
                    }
                } else {                      // rows i>=p+2: double update
                    float2 Upi = sAugU[rop + i - p];
                    float m0x = Upi.x * i0x + Upi.y * i0y;     // conj(Upi)*inv0
                    float m0y = Upi.x * i0y - Upi.y * i0x;
                    float2 Uqi = sAugU[roq + i - q];
                    float ax = Uqi.x - (m0x * Upq.x - m0y * Upq.y);   // A1[i][q]
                    float ay = -Uqi.y - (m0x * Upq.y + m0y * Upq.x);
                    float m1x = ax * i1x - ay * i1y;           // m1 = a*inv1
                    float m1y = ax * i1y + ay * i1x;
                    int roi = rowoff(i) - i;
#pragma unroll 1
                    for (int j = i + ci; j < NA; j += 16) {
                        float2 Upj = sAugU[rop + j - p];
                        float2 Uqj = sAugU[roq + j - q];
                        float u1x = Uqj.x - (mqx * Upj.x - mqy * Upj.y);
                        float u1y = Uqj.y - (mqx * Upj.y + mqy * Upj.x);
                        float2 v = sAugU[roi + j];
                        v.x -= (m0x * Upj.x - m0y * Upj.y) + (m1x * u1x - m1y * u1y);
                        v.y -= (m0x * Upj.y + m0y * Upj.x) + (m1x * u1y + m1y * u1x);
                        sAugU[roi + j] = v;
                    }
                }
            }
            __syncthreads();
        }
        // final single pivot p=38 (+ flush deferred row 37)
        {
            int p = N_ - 2;
            if (ri == 0) {
                int qm = p - 1, roqm = rowoff(qm);
                if (ci < NA - qm)      sAugU[roqm + ci] = dq0;
                if (ci + 16 < NA - qm) sAugU[roqm + ci + 16] = dq1;
                if (ci + 32 < NA - qm) sAugU[roqm + ci + 32] = dq2;
            }
            int rop = rowoff(p);
            float2 piv = sAugU[rop];
            float dn = piv.x * piv.x + piv.y * piv.y;
            float px = piv.x / dn, py = -piv.y / dn;
#pragma unroll 1
            for (int i = p + 1 + ri; i < N_; i += 24) {
                float2 api = sAugU[rop + i - p];
                float mx = api.x * px + api.y * py;
                float my = api.x * py - api.y * px;
                int roi = rowoff(i) - i;
#pragma unroll 1
                for (int j = i + ci; j < NA; j += 16) {
                    float2 apj = sAugU[rop + j - p];
                    float2 v = sAugU[roi + j];
                    v.x -= mx * apj.x - my * apj.y;
                    v.y -= mx * apj.y + my * apj.x;
                    sAugU[roi + j] = v;
                }
            }
            __syncthreads();
        }
    }
    // ---- backward elimination on RHS, TWO pivots (p,q=p-1) per interval.
    //      48 row-groups x 8 cols: i-loop is a single iteration. ----
    {
        int bc = tid & 7, br = tid >> 3;     // br 0..47
        float2 defv = make_float2(0.f, 0.f);
        int defRow = -1;
#pragma unroll 1
        for (int p = N_ - 1; p >= 3; p -= 2) {
            if (defRow >= 0 && br == (defRow & 31))
                sAugU[rowoff(defRow) + N_ + bc - defRow] = defv;
            int q = p - 1;
            int rop = rowoff(p), roq = rowoff(q);
            float2 pivP = sAugU[rop];
            float dnP = pivP.x * pivP.x + pivP.y * pivP.y;
            float pPx = pivP.x / dnP, pPy = -pivP.y / dnP;
            float2 rhsP = sAugU[rop + N_ + bc - p];
            float xPx = rhsP.x * pPx - rhsP.y * pPy;
            float xPy = rhsP.x * pPy + rhsP.y * pPx;
            float2 pivQ = sAugU[roq];
            float dnQ = pivQ.x * pivQ.x + pivQ.y * pivQ.y;
            float pQx = pivQ.x / dnQ, pQy = -pivQ.y / dnQ;
            float2 Uqp = sAugU[roq + 1];                 // U[p-1][p]
            float2 rhsQ = sAugU[roq + N_ + bc - q];
            float rqx = rhsQ.x - (Uqp.x * xPx - Uqp.y * xPy);   // rhs'[q]
            float rqy = rhsQ.y - (Uqp.x * xPy + Uqp.y * xPx);
            float xQx = rqx * pQx - rqy * pQy;
            float xQy = rqx * pQy + rqy * pQx;
            if (br <= p - 2) {
                int i = br;
                int roi = rowoff(i) - i;
                float2 Uip = sAugU[roi + p];
                float2 Uiq = sAugU[roi + q];
                float2 v = sAugU[roi + N_ + bc];
                v.x -= (Uip.x * xPx - Uip.y * xPy) + (Uiq.x * xQx - Uiq.y * xQy);
                v.y -= (Uip.x * xPy + Uip.y * xPx) + (Uiq.x * xQy + Uiq.y * xQx);
                sAugU[roi + N_ + bc] = v;
            }
            if (br == (q & 31)) defv = make_float2(rqx, rqy);
            defRow = q;
            __syncthreads();
        }
        // single pivot p=1 (+ flush deferred rhs row 2)
        {
            if (defRow >= 0 && br == (defRow & 31))
                sAugU[rowoff(defRow) + N_ + bc - defRow] = defv;
            int rop = rowoff(1);
            float2 piv = sAugU[rop];
            float dn = piv.x * piv.x + piv.y * piv.y;
            float px = piv.x / dn, py = -piv.y / dn;
            float2 rhs = sAugU[rop + N_ + bc - 1];
            float xr = rhs.x * px - rhs.y * py;
            float xi = rhs.x * py + rhs.y * px;
            if (br == 0) {
                float2 aip = sAugU[1];                   // U[0][1] (rowoff(0)=0)
                float2 v = sAugU[N_ + bc];               // rhs[0]
                v.x -= aip.x * xr - aip.y * xi;
                v.y -= aip.x * xi + aip.y * xr;
                sAugU[N_ + bc] = v;
            }
            __syncthreads();
        }
    }
    // ---- G divide IN PLACE: rhs[j][e] /= diag[j] (diag and rhs slots disjoint) ----
    if (tid < N_ * C_) {
        int j = tid >> 3;
        int e = tid & 7;
        int roj = rowoff(j);
        float2 piv = sAugU[roj];
        float dnm = piv.x * piv.x + piv.y * piv.y;
        float pix = piv.x / dnm, piy = -piv.y / dnm;
        float2 rhs = sAugU[roj + N_ + e - j];
        sAugU[roj + N_ + e - j] =
            make_float2(rhs.x * pix - rhs.y * piy, rhs.x * piy + rhs.y * pix);
    }
    __syncthreads();

    // ---- A fragments read from in-place G (f16 cast; threshold 0.134).
    //      Only waves 0-3 run the tail MFMAs. ----
    half8 aFr[2] = {}, aFi[2] = {};
    if (wv < 4) {
        int m = ln & 15;
#pragma unroll
        for (int ks = 0; ks < 2; ++ks) {
            half8 hr = {}, hi = {};
#pragma unroll
            for (int q = 0; q < 8; ++q) {
                int j = ks * 32 + kg * 8 + q;
                float gx = 0.f, gy = 0.f;
                if (m < 8 && j < N_) {
                    float2 g = sAugU[rowoff(j) + N_ + m - j];
                    gx = g.x; gy = g.y;
                }
                hr[q] = (_Float16)gx;
                hi[q] = (_Float16)gy;
            }
            aFr[ks] = hr;
            aFi[ks] = hi;
        }
    }
    __syncthreads();   // sAugU reads done -> pool becomes zRe/zIm planes

    // ================= MFMA tail =================
    // tail[e][t] = sum_j G[j][e]*Zraw[j][t]. 64-t chunks; all 6 waves build
    // both planes; waves 0-3 run the 8 complex MFMAs (trow covers 64 t).
    uint32_t* zRe = pool;                    // [64][ZSD]
    uint32_t* zIm = pool + 64 * ZSD;         // [64][ZSD]
    int trow = wv * 16 + (ln & 15);
#pragma unroll 1
    for (int ch = 0; ch < 8; ++ch) {
        int c0 = ch * 64;
        for (int idx = tid; idx < 1280; idx += NTHR) {
            int jp = idx >> 6, tl = idx & 63;
            int j0 = 2 * jp, j1 = j0 + 1;
            int base = c0 + tl + (YPAD - 3);
            uint32_t y0 = sYh[(j0 & 7) * YSH + base - (j0 >> 3)];
            uint32_t y1 = sYh[(j1 & 7) * YSH + base - (j1 >> 3)];
            zRe[tl * ZSD + jp] = __builtin_amdgcn_perm(y1, y0, 0x05040100);
            zIm[tl * ZSD + jp] = __builtin_amdgcn_perm(y1, y0, 0x07060302);
        }
        __syncthreads();
        if (wv < 4) {
            floatx4 accR = {0.f, 0.f, 0.f, 0.f};
            floatx4 accI = {0.f, 0.f, 0.f, 0.f};
            {
                int o0 = trow * ZSD + kg * 4;
                half8 Br0 = __builtin_bit_cast(half8, *(const uint32x4*)&zRe[o0]);
                half8 Bi0 = __builtin_bit_cast(half8, *(const uint32x4*)&zIm[o0]);
                half8 Br1 = {}, Bi1 = {};
                if (kg == 0) {
                    int o1 = trow * ZSD + 16;
                    Br1 = __builtin_bit_cast(half8, *(const uint32x4*)&zRe[o1]);
                    Bi1 = __builtin_bit_cast(half8, *(const uint32x4*)&zIm[o1]);
                }
                half8 nFi0 = -aFi[0], nFi1 = -aFi[1];
                accR = __builtin_amdgcn_mfma_f32_16x16x32_f16(aFr[0], Br0, accR, 0, 0, 0);
                accR = __builtin_amdgcn_mfma_f32_16x16x32_f16(aFr[1], Br1, accR, 0, 0, 0);
                accI = __builtin_amdgcn_mfma_f32_16x16x32_f16(aFi[0], Br0, accI, 0, 0, 0);
                accI = __builtin_amdgcn_mfma_f32_16x16x32_f16(aFi[1], Br1, accI, 0, 0, 0);
                accR = __builtin_amdgcn_mfma_f32_16x16x32_f16(nFi0, Bi0, accR, 0, 0, 0);
                accR = __builtin_amdgcn_mfma_f32_16x16x32_f16(nFi1, Bi1, accR, 0, 0, 0);
                accI = __builtin_amdgcn_mfma_f32_16x16x32_f16(aFr[0], Bi0, accI, 0, 0, 0);
                accI = __builtin_amdgcn_mfma_f32_16x16x32_f16(aFr[1], Bi1, accI, 0, 0, 0);
            }
            if (kg < 2) {
                int tg = c0 + trow;
                bool dead = (tg >= ilen);
#pragma unroll
                for (int r = 0; r < 4; ++r) {
                    int e = kg * 4 + r;
                    float2 cf = unpackf16(sYh[e * YSH + YPAD + tg]);
                    float ex = cf.x - accR[r];
                    float ey = cf.y - accI[r];
                    if (dead) { ex = 0.f; ey = 0.f; }
                    size_t o = (size_t)b * T_ * C_ * F_ + ((size_t)tg * C_ + e) * F_ + f;
                    out_re[o] = ex;
                    out_im[o] = ey;
                }
            }
        }
        __syncthreads();   // WAR: next chunk's build overwrites planes
    }
}

extern "C" void kernel_launch(void* const* d_in, const int* in_sizes, int n_in,
                              void* d_out, int out_size, void* d_ws, size_t ws_size,
                              hipStream_t stream) {
    const float* in_re = (const float*)d_in[0];
    const float* in_im = (const float*)d_in[1];
    const int* ilens = (const int*)d_in[2];

    float* out_re = (float*)d_out;
    float* out_im = out_re + BTCF;
    float* out_pw = out_im + BTCF;   // (B,F,T) float32

    // Single fused kernel: no transposes, no workspace.
    k_fused<<<BF, NTHR, 0, stream>>>(in_re, in_im, ilens, out_re, out_im, out_pw);
}